// Round 1
// baseline (582.433 us; speedup 1.0000x reference)
//
#include <hip/hip_runtime.h>

typedef __attribute__((ext_vector_type(8))) short bf16x8;
typedef __attribute__((ext_vector_type(4))) short s16x4;
typedef __attribute__((ext_vector_type(4))) float f32x4;

#define MFMA16(a,b,c) __builtin_amdgcn_mfma_f32_16x16x32_bf16((a),(b),(c),0,0,0)

static constexpr int Bsz = 4, T = 2048, E = 1024, NH = 16, HP = 64;
static constexpr int BT = Bsz * T;      // 8192
static constexpr int J3 = NH * 3 * HP;  // 3072

__device__ __forceinline__ short f2bf(float f) {
  union { float f; unsigned u; } v; v.f = f;
  unsigned r = (v.u + 0x7fffu + ((v.u >> 16) & 1u)) >> 16;
  return (short)r;
}

// ---------------- converts ----------------
__global__ void cvt_x(const float4* __restrict__ x, s16x4* __restrict__ xb) {
  int i = blockIdx.x * 256 + threadIdx.x;   // 2,097,152 threads, 4 f32 each
  float4 v = x[i];
  s16x4 r;
  r[0] = f2bf(v.x); r[1] = f2bf(v.y); r[2] = f2bf(v.z); r[3] = f2bf(v.w);
  xb[i] = r;
}

// w_qkv [E=1024][J=3072] f32  ->  wt [J][E] bf16 (B^T layout)
__global__ void cvt_wqkv(const float* __restrict__ w, short* __restrict__ wt) {
  __shared__ float tile[32][33];
  int jb = blockIdx.x * 32, eb = blockIdx.y * 32;
  int tx = threadIdx.x & 31, ty = threadIdx.x >> 5;   // 32x8
  for (int r = 0; r < 32; r += 8)
    tile[ty + r][tx] = w[(size_t)(eb + ty + r) * J3 + jb + tx];
  __syncthreads();
  for (int r = 0; r < 32; r += 8)
    wt[(size_t)(jb + ty + r) * E + eb + tx] = f2bf(tile[tx][ty + r]);
}

// w_o [P=64][N=16][E=1024] f32 -> wt [e][k'=n*64+p] bf16 (B^T layout, K-dim k')
__global__ void cvt_wo(const float* __restrict__ w, short* __restrict__ wt) {
  int o = blockIdx.x * 256 + threadIdx.x;  // 1,048,576
  int e = o >> 10, k = o & 1023;
  int n = k >> 6, p = k & 63;
  wt[o] = f2bf(w[(size_t)(p * 16 + n) * E + e]);
}

// ---------------- GEMM1: qkv = x @ w_qkv, scatter to Q (scaled 1/8), K, V^T ----------------
__global__ __launch_bounds__(256) void gemm_qkv(
    const short* __restrict__ A,    // xb [8192][1024]
    const short* __restrict__ Bt,   // wqkvbT [3072][1024]
    const float* __restrict__ bias, // b_qkv flat [3072]
    short* __restrict__ Qb, short* __restrict__ Kb, short* __restrict__ Vt) {
  __shared__ short As[128 * 40];
  __shared__ short Bs[128 * 40];
  const int m0 = blockIdx.x * 128, n0 = blockIdx.y * 128;
  const int tid = threadIdx.x;
  const int lane = tid & 63, w = tid >> 6;
  const int wm = (w >> 1) * 64, wn = (w & 1) * 64;
  const int l15 = lane & 15, lh = lane >> 4;
  const int srow = tid >> 1, soff = (tid & 1) * 16;

  const short* Ap = A + (size_t)(m0 + srow) * 1024 + soff;
  const short* Bp = Bt + (size_t)(n0 + srow) * 1024 + soff;
  f32x4 acc[4][4] = {};

  for (int k0 = 0; k0 < 1024; k0 += 32) {
    bf16x8 a0 = *(const bf16x8*)(Ap + k0);
    bf16x8 a1 = *(const bf16x8*)(Ap + k0 + 8);
    bf16x8 b0 = *(const bf16x8*)(Bp + k0);
    bf16x8 b1 = *(const bf16x8*)(Bp + k0 + 8);
    __syncthreads();
    *(bf16x8*)(As + srow * 40 + soff) = a0;
    *(bf16x8*)(As + srow * 40 + soff + 8) = a1;
    *(bf16x8*)(Bs + srow * 40 + soff) = b0;
    *(bf16x8*)(Bs + srow * 40 + soff + 8) = b1;
    __syncthreads();
    bf16x8 af[4], bfr[4];
#pragma unroll
    for (int m = 0; m < 4; m++) af[m] = *(const bf16x8*)(As + (wm + m * 16 + l15) * 40 + 8 * lh);
#pragma unroll
    for (int n = 0; n < 4; n++) bfr[n] = *(const bf16x8*)(Bs + (wn + n * 16 + l15) * 40 + 8 * lh);
#pragma unroll
    for (int m = 0; m < 4; m++)
#pragma unroll
      for (int n = 0; n < 4; n++)
        acc[m][n] = MFMA16(af[m], bfr[n], acc[m][n]);
  }

#pragma unroll
  for (int nn = 0; nn < 4; nn++) {
    int j = n0 + wn + nn * 16 + l15;
    int nh = j / 192, c = j - nh * 192;
    int ty = c >> 6, p = c & 63;   // ty uniform per 16-col subtile (64-aligned splits)
    float bv = bias[j];
#pragma unroll
    for (int mm = 0; mm < 4; mm++) {
#pragma unroll
      for (int r = 0; r < 4; r++) {
        int i = m0 + wm + mm * 16 + lh * 4 + r;
        int bb = i >> 11, tt = i & 2047;
        float val = acc[mm][nn][r] + bv;
        size_t qk = (((size_t)(bb * 16 + nh) * 2048 + tt) << 6) + p;
        if (ty == 0)      Qb[qk] = f2bf(val * 0.125f);   // fold 1/sqrt(P)
        else if (ty == 1) Kb[qk] = f2bf(val);
        else Vt[(((size_t)(bb * 16 + nh) << 6) + p) * 2048 + tt] = f2bf(val);  // V transposed
      }
    }
  }
}

// ---------------- flash attention: per (b,n) head, 64 q-rows per block ----------------
__global__ __launch_bounds__(256) void attn(
    const short* __restrict__ Qb, const short* __restrict__ Kb,
    const short* __restrict__ Vt, short* __restrict__ Wt) {
  __shared__ short Pl[4][16 * 72];
  const int bid = blockIdx.x;            // 2048
  const int qb = bid & 31, bn = bid >> 5;
  const int tid = threadIdx.x, lane = tid & 63, w = tid >> 6;
  const int l15 = lane & 15, lh = lane >> 4;
  const int q0 = qb * 64 + w * 16;

  const short* Qp = Qb + ((size_t)bn * 2048 + q0) * 64;
  const short* Kp = Kb + (size_t)bn * 2048 * 64;
  const short* Vp = Vt + (size_t)bn * 64 * 2048;
  short* Pw = &Pl[w][0];

  bf16x8 aq0 = *(const bf16x8*)(Qp + l15 * 64 + 8 * lh);
  bf16x8 aq1 = *(const bf16x8*)(Qp + l15 * 64 + 32 + 8 * lh);

  float mreg[4], lsum[4];
  f32x4 o[4] = {};
#pragma unroll
  for (int r = 0; r < 4; r++) { mreg[r] = -INFINITY; lsum[r] = 0.f; }
  const f32x4 zero = {0.f, 0.f, 0.f, 0.f};

  for (int kv0 = 0; kv0 < 2048; kv0 += 64) {
    f32x4 s[4];
#pragma unroll
    for (int sub = 0; sub < 4; sub++) {
      const short* kb = Kp + (size_t)(kv0 + sub * 16 + l15) * 64 + 8 * lh;
      bf16x8 k0 = *(const bf16x8*)(kb);
      bf16x8 k1 = *(const bf16x8*)(kb + 32);
      f32x4 t = MFMA16(aq0, k0, zero);
      s[sub] = MFMA16(aq1, k1, t);
    }
    // online softmax: lane holds rows q=4*lh+r, cols kv=l15+16*sub
#pragma unroll
    for (int r = 0; r < 4; r++) {
      float mx = fmaxf(fmaxf(s[0][r], s[1][r]), fmaxf(s[2][r], s[3][r]));
#pragma unroll
      for (int d = 1; d < 16; d <<= 1) mx = fmaxf(mx, __shfl_xor(mx, d, 64));
      float mn = fmaxf(mreg[r], mx);
      float corr = __expf(mreg[r] - mn);
      mreg[r] = mn;
      float ps = 0.f;
#pragma unroll
      for (int sub = 0; sub < 4; sub++) {
        float pv = __expf(s[sub][r] - mn);
        s[sub][r] = pv;
        ps += pv;
      }
#pragma unroll
      for (int d = 1; d < 16; d <<= 1) ps += __shfl_xor(ps, d, 64);
      lsum[r] = lsum[r] * corr + ps;
#pragma unroll
      for (int psub = 0; psub < 4; psub++) o[psub][r] *= corr;
#pragma unroll
      for (int sub = 0; sub < 4; sub++)
        Pw[(lh * 4 + r) * 72 + sub * 16 + l15] = f2bf(s[sub][r]);
    }
    // PV: A = P from LDS (A-frag layout), B = V^T rows (contiguous)
    bf16x8 pa0 = *(const bf16x8*)(Pw + l15 * 72 + 8 * lh);
    bf16x8 pa1 = *(const bf16x8*)(Pw + l15 * 72 + 32 + 8 * lh);
#pragma unroll
    for (int psub = 0; psub < 4; psub++) {
      const short* vb = Vp + (size_t)(psub * 16 + l15) * 2048 + kv0 + 8 * lh;
      bf16x8 v0 = *(const bf16x8*)(vb);
      bf16x8 v1 = *(const bf16x8*)(vb + 32);
      o[psub] = MFMA16(pa0, v0, o[psub]);
      o[psub] = MFMA16(pa1, v1, o[psub]);
    }
  }

  float inv[4];
#pragma unroll
  for (int r = 0; r < 4; r++) inv[r] = 1.0f / lsum[r];
  const int bb = bn >> 4, n = bn & 15;
#pragma unroll
  for (int psub = 0; psub < 4; psub++)
#pragma unroll
    for (int r = 0; r < 4; r++) {
      int q = q0 + lh * 4 + r;
      Wt[(size_t)(bb * 2048 + q) * 1024 + n * 64 + psub * 16 + l15] =
          f2bf(o[psub][r] * inv[r]);
    }
}

// ---------------- GEMM2: out = weighted @ w_o + b_o (f32 out) ----------------
__global__ __launch_bounds__(256) void gemm_o(
    const short* __restrict__ A,   // Wt [8192][1024]
    const short* __restrict__ Bt,  // wobT [1024][1024]
    const float* __restrict__ bo,  // [1024]
    float* __restrict__ out) {     // [8192][1024]
  __shared__ short As[128 * 40];
  __shared__ short Bs[128 * 40];
  const int m0 = blockIdx.x * 128, n0 = blockIdx.y * 128;
  const int tid = threadIdx.x;
  const int lane = tid & 63, w = tid >> 6;
  const int wm = (w >> 1) * 64, wn = (w & 1) * 64;
  const int l15 = lane & 15, lh = lane >> 4;
  const int srow = tid >> 1, soff = (tid & 1) * 16;

  const short* Ap = A + (size_t)(m0 + srow) * 1024 + soff;
  const short* Bp = Bt + (size_t)(n0 + srow) * 1024 + soff;
  f32x4 acc[4][4] = {};

  for (int k0 = 0; k0 < 1024; k0 += 32) {
    bf16x8 a0 = *(const bf16x8*)(Ap + k0);
    bf16x8 a1 = *(const bf16x8*)(Ap + k0 + 8);
    bf16x8 b0 = *(const bf16x8*)(Bp + k0);
    bf16x8 b1 = *(const bf16x8*)(Bp + k0 + 8);
    __syncthreads();
    *(bf16x8*)(As + srow * 40 + soff) = a0;
    *(bf16x8*)(As + srow * 40 + soff + 8) = a1;
    *(bf16x8*)(Bs + srow * 40 + soff) = b0;
    *(bf16x8*)(Bs + srow * 40 + soff + 8) = b1;
    __syncthreads();
    bf16x8 af[4], bfr[4];
#pragma unroll
    for (int m = 0; m < 4; m++) af[m] = *(const bf16x8*)(As + (wm + m * 16 + l15) * 40 + 8 * lh);
#pragma unroll
    for (int n = 0; n < 4; n++) bfr[n] = *(const bf16x8*)(Bs + (wn + n * 16 + l15) * 40 + 8 * lh);
#pragma unroll
    for (int m = 0; m < 4; m++)
#pragma unroll
      for (int n = 0; n < 4; n++)
        acc[m][n] = MFMA16(af[m], bfr[n], acc[m][n]);
  }

#pragma unroll
  for (int nn = 0; nn < 4; nn++) {
    int e = n0 + wn + nn * 16 + l15;
    float bv = bo[e];
#pragma unroll
    for (int mm = 0; mm < 4; mm++) {
#pragma unroll
      for (int r = 0; r < 4; r++) {
        int i = m0 + wm + mm * 16 + lh * 4 + r;
        out[(size_t)i * 1024 + e] = acc[mm][nn][r] + bv;
      }
    }
  }
}

extern "C" void kernel_launch(void* const* d_in, const int* in_sizes, int n_in,
                              void* d_out, int out_size, void* d_ws, size_t ws_size,
                              hipStream_t stream) {
  (void)in_sizes; (void)n_in; (void)out_size; (void)ws_size;
  const float* x     = (const float*)d_in[0];
  const float* w_qkv = (const float*)d_in[1];
  const float* b_qkv = (const float*)d_in[2];
  const float* w_o   = (const float*)d_in[3];
  const float* b_o   = (const float*)d_in[4];
  float* out = (float*)d_out;
  char* ws = (char*)d_ws;

  short* xb     = (short*)(ws);               // 16.8 MB  [8192][1024]
  short* wqkvbT = (short*)(ws + 16777216);    //  6.3 MB  [3072][1024]
  short* wobT   = (short*)(ws + 23068672);    //  2.1 MB  [1024][1024]
  short* Qb     = (short*)(ws + 25165824);    // 16.8 MB  [64][2048][64]
  short* Kb     = (short*)(ws + 41943040);    // 16.8 MB  [64][2048][64]
  short* Vt     = (short*)(ws + 58720256);    // 16.8 MB  [64][64][2048]
  short* Wt     = (short*)(ws + 75497472);    // 16.8 MB  [8192][1024]

  hipLaunchKernelGGL(cvt_x,    dim3(8192),    dim3(256), 0, stream, (const float4*)x, (s16x4*)xb);
  hipLaunchKernelGGL(cvt_wqkv, dim3(96, 32),  dim3(256), 0, stream, w_qkv, wqkvbT);
  hipLaunchKernelGGL(cvt_wo,   dim3(4096),    dim3(256), 0, stream, w_o, wobT);
  hipLaunchKernelGGL(gemm_qkv, dim3(64, 24),  dim3(256), 0, stream, xb, wqkvbT, b_qkv, Qb, Kb, Vt);
  hipLaunchKernelGGL(attn,     dim3(2048),    dim3(256), 0, stream, Qb, Kb, Vt, Wt);
  hipLaunchKernelGGL(gemm_o,   dim3(64, 8),   dim3(256), 0, stream, Wt, wobT, b_o, out);
}

// Round 2
// 580.082 us; speedup vs baseline: 1.0041x; 1.0041x over previous
//
#include <hip/hip_runtime.h>

typedef __attribute__((ext_vector_type(8))) short bf16x8;
typedef __attribute__((ext_vector_type(4))) short s16x4;
typedef __attribute__((ext_vector_type(4))) float f32x4;

#define MFMA16(a,b,c) __builtin_amdgcn_mfma_f32_16x16x32_bf16((a),(b),(c),0,0,0)

static constexpr int Bsz = 4, T = 2048, E = 1024, NH = 16, HP = 64;
static constexpr int BT = Bsz * T;      // 8192
static constexpr int J3 = NH * 3 * HP;  // 3072

__device__ __forceinline__ short f2bf(float f) {
  union { float f; unsigned u; } v; v.f = f;
  unsigned r = (v.u + 0x7fffu + ((v.u >> 16) & 1u)) >> 16;
  return (short)r;
}

// ---------------- converts ----------------
__global__ void cvt_x(const float4* __restrict__ x, s16x4* __restrict__ xb) {
  int i = blockIdx.x * 256 + threadIdx.x;
  float4 v = x[i];
  s16x4 r;
  r[0] = f2bf(v.x); r[1] = f2bf(v.y); r[2] = f2bf(v.z); r[3] = f2bf(v.w);
  xb[i] = r;
}

// w_qkv [E=1024][J=3072] f32  ->  wt [J][E] bf16 (B^T layout)
__global__ void cvt_wqkv(const float* __restrict__ w, short* __restrict__ wt) {
  __shared__ float tile[32][33];
  int jb = blockIdx.x * 32, eb = blockIdx.y * 32;
  int tx = threadIdx.x & 31, ty = threadIdx.x >> 5;   // 32x8
  for (int r = 0; r < 32; r += 8)
    tile[ty + r][tx] = w[(size_t)(eb + ty + r) * J3 + jb + tx];
  __syncthreads();
  for (int r = 0; r < 32; r += 8)
    wt[(size_t)(jb + ty + r) * E + eb + tx] = f2bf(tile[tx][ty + r]);
}

// w_o [P=64][N=16][E=1024] f32 -> wt [e][k'=n*64+p] bf16 (B^T layout, K-dim k')
__global__ void cvt_wo(const float* __restrict__ w, short* __restrict__ wt) {
  int o = blockIdx.x * 256 + threadIdx.x;
  int e = o >> 10, k = o & 1023;
  int n = k >> 6, p = k & 63;
  wt[o] = f2bf(w[(size_t)(p * 16 + n) * E + e]);
}

// ---------------- GEMM1: qkv = x @ w_qkv, scatter to Q (scaled), K, V^T ----------------
__global__ __launch_bounds__(256) void gemm_qkv(
    const short* __restrict__ A,    // xb [8192][1024]
    const short* __restrict__ Bt,   // wqkvbT [3072][1024]
    const float* __restrict__ bias, // b_qkv flat [3072]
    short* __restrict__ Qb, short* __restrict__ Kb, short* __restrict__ Vt) {
  __shared__ short As[128 * 40];
  __shared__ short Bs[128 * 40];
  const int m0 = blockIdx.x * 128, n0 = blockIdx.y * 128;
  const int tid = threadIdx.x;
  const int lane = tid & 63, w = tid >> 6;
  const int wm = (w >> 1) * 64, wn = (w & 1) * 64;
  const int l15 = lane & 15, lh = lane >> 4;
  const int srow = tid >> 1, soff = (tid & 1) * 16;

  const short* Ap = A + (size_t)(m0 + srow) * 1024 + soff;
  const short* Bp = Bt + (size_t)(n0 + srow) * 1024 + soff;
  f32x4 acc[4][4] = {};

  for (int k0 = 0; k0 < 1024; k0 += 32) {
    bf16x8 a0 = *(const bf16x8*)(Ap + k0);
    bf16x8 a1 = *(const bf16x8*)(Ap + k0 + 8);
    bf16x8 b0 = *(const bf16x8*)(Bp + k0);
    bf16x8 b1 = *(const bf16x8*)(Bp + k0 + 8);
    __syncthreads();
    *(bf16x8*)(As + srow * 40 + soff) = a0;
    *(bf16x8*)(As + srow * 40 + soff + 8) = a1;
    *(bf16x8*)(Bs + srow * 40 + soff) = b0;
    *(bf16x8*)(Bs + srow * 40 + soff + 8) = b1;
    __syncthreads();
    bf16x8 af[4], bfr[4];
#pragma unroll
    for (int m = 0; m < 4; m++) af[m] = *(const bf16x8*)(As + (wm + m * 16 + l15) * 40 + 8 * lh);
#pragma unroll
    for (int n = 0; n < 4; n++) bfr[n] = *(const bf16x8*)(Bs + (wn + n * 16 + l15) * 40 + 8 * lh);
#pragma unroll
    for (int m = 0; m < 4; m++)
#pragma unroll
      for (int n = 0; n < 4; n++)
        acc[m][n] = MFMA16(af[m], bfr[n], acc[m][n]);
  }

#pragma unroll
  for (int nn = 0; nn < 4; nn++) {
    int j = n0 + wn + nn * 16 + l15;
    int nh = j / 192, c = j - nh * 192;
    int ty = c >> 6, p = c & 63;
    float bv = bias[j];
#pragma unroll
    for (int mm = 0; mm < 4; mm++) {
#pragma unroll
      for (int r = 0; r < 4; r++) {
        int i = m0 + wm + mm * 16 + lh * 4 + r;
        int bb = i >> 11, tt = i & 2047;
        float val = acc[mm][nn][r] + bv;
        size_t qk = (((size_t)(bb * 16 + nh) * 2048 + tt) << 6) + p;
        // fold 1/sqrt(P) * log2(e) into Q so attention can use raw exp2
        if (ty == 0)      Qb[qk] = f2bf(val * 0.180336880f);
        else if (ty == 1) Kb[qk] = f2bf(val);
        else Vt[(((size_t)(bb * 16 + nh) << 6) + p) * 2048 + tt] = f2bf(val);  // V transposed
      }
    }
  }
}

// ---------------- flash attention, swapped-operand form ----------------
// S^T = mfma(K, Q): lane holds 16 scores of ONE q-row (q = lane&15).
// O^T = mfma(Vt, P): output col = q = lane&15 -> rescale/div are lane-local.
__global__ __launch_bounds__(256) void attn(
    const short* __restrict__ Qb, const short* __restrict__ Kb,
    const short* __restrict__ Vt, short* __restrict__ Wt) {
  __shared__ short Pl[4][16 * 72];
  const int bid = blockIdx.x;            // 2048
  const int qb = bid & 31, bn = bid >> 5;
  const int tid = threadIdx.x, lane = tid & 63, w = tid >> 6;
  const int l15 = lane & 15, lh = lane >> 4;
  const int q0 = qb * 64 + w * 16;

  const short* Qp = Qb + ((size_t)bn * 2048 + q0) * 64;
  const short* Kp = Kb + (size_t)bn * 2048 * 64;
  const short* Vp = Vt + (size_t)bn * 64 * 2048;
  short* Pw = &Pl[w][0];

  // Q fragments (B-operand): rows q = q0 + l15
  bf16x8 qf0 = *(const bf16x8*)(Qp + l15 * 64 + 8 * lh);
  bf16x8 qf1 = *(const bf16x8*)(Qp + l15 * 64 + 32 + 8 * lh);

  float m = -1e30f, l = 0.f;
  f32x4 o[4] = {};
  const f32x4 zero = {0.f, 0.f, 0.f, 0.f};

  for (int kv0 = 0; kv0 < 2048; kv0 += 64) {
    // QK^T (swapped): s[sub][r] = S[kv = kv0+sub*16+lh*4+r][q = q0+l15]
    f32x4 s[4];
#pragma unroll
    for (int sub = 0; sub < 4; sub++) {
      const short* kb = Kp + (size_t)(kv0 + sub * 16 + l15) * 64 + 8 * lh;
      bf16x8 k0 = *(const bf16x8*)(kb);
      bf16x8 k1 = *(const bf16x8*)(kb + 32);
      f32x4 t = MFMA16(k0, qf0, zero);
      s[sub] = MFMA16(k1, qf1, t);
    }
    // in-lane row max over 16 scores + 2-shfl cross-group reduce
    float mx = fmaxf(fmaxf(s[0][0], s[0][1]), fmaxf(s[0][2], s[0][3]));
#pragma unroll
    for (int sub = 1; sub < 4; sub++)
      mx = fmaxf(mx, fmaxf(fmaxf(s[sub][0], s[sub][1]), fmaxf(s[sub][2], s[sub][3])));
    mx = fmaxf(mx, __shfl_xor(mx, 16, 64));
    mx = fmaxf(mx, __shfl_xor(mx, 32, 64));
    float mn = fmaxf(m, mx);
    float corr = __builtin_amdgcn_exp2f(m - mn);
    m = mn;
    // exp2 (log2e pre-folded into Q) + in-lane sum + 2-shfl reduce
    float ps = 0.f;
#pragma unroll
    for (int sub = 0; sub < 4; sub++) {
      s16x4 pk;
#pragma unroll
      for (int r = 0; r < 4; r++) {
        float pv = __builtin_amdgcn_exp2f(s[sub][r] - mn);
        ps += pv;
        pk[r] = f2bf(pv);
      }
      *(s16x4*)(Pw + l15 * 72 + sub * 16 + lh * 4) = pk;  // 8B packed write
    }
    ps += __shfl_xor(ps, 16, 64);
    ps += __shfl_xor(ps, 32, 64);
    l = l * corr + ps;
    // rescale O by lane-local corr
#pragma unroll
    for (int psub = 0; psub < 4; psub++)
#pragma unroll
      for (int r = 0; r < 4; r++) o[psub][r] *= corr;
    // PV (swapped): A = Vt rows (p), B = P rows (q) from LDS
    bf16x8 pa0 = *(const bf16x8*)(Pw + l15 * 72 + 8 * lh);
    bf16x8 pa1 = *(const bf16x8*)(Pw + l15 * 72 + 32 + 8 * lh);
#pragma unroll
    for (int psub = 0; psub < 4; psub++) {
      const short* vb = Vp + (size_t)(psub * 16 + l15) * 2048 + kv0 + 8 * lh;
      bf16x8 v0 = *(const bf16x8*)(vb);
      bf16x8 v1 = *(const bf16x8*)(vb + 32);
      o[psub] = MFMA16(v0, pa0, o[psub]);
      o[psub] = MFMA16(v1, pa1, o[psub]);
    }
  }

  const float invl = 1.0f / l;
  const int bb = bn >> 4, n = bn & 15;
  // lane holds O[p = psub*16+lh*4+r][q = l15]; pack 4 p-consecutive bf16
  short* wrow = Wt + (size_t)(bb * 2048 + q0 + l15) * 1024 + n * 64;
#pragma unroll
  for (int psub = 0; psub < 4; psub++) {
    s16x4 pk;
#pragma unroll
    for (int r = 0; r < 4; r++) pk[r] = f2bf(o[psub][r] * invl);
    *(s16x4*)(wrow + psub * 16 + lh * 4) = pk;
  }
}

// ---------------- GEMM2: out = weighted @ w_o + b_o (f32 out) ----------------
__global__ __launch_bounds__(256) void gemm_o(
    const short* __restrict__ A,   // Wt [8192][1024]
    const short* __restrict__ Bt,  // wobT [1024][1024]
    const float* __restrict__ bo,  // [1024]
    float* __restrict__ out) {     // [8192][1024]
  __shared__ short As[128 * 40];
  __shared__ short Bs[128 * 40];
  const int m0 = blockIdx.x * 128, n0 = blockIdx.y * 128;
  const int tid = threadIdx.x;
  const int lane = tid & 63, w = tid >> 6;
  const int wm = (w >> 1) * 64, wn = (w & 1) * 64;
  const int l15 = lane & 15, lh = lane >> 4;
  const int srow = tid >> 1, soff = (tid & 1) * 16;

  const short* Ap = A + (size_t)(m0 + srow) * 1024 + soff;
  const short* Bp = Bt + (size_t)(n0 + srow) * 1024 + soff;
  f32x4 acc[4][4] = {};

  for (int k0 = 0; k0 < 1024; k0 += 32) {
    bf16x8 a0 = *(const bf16x8*)(Ap + k0);
    bf16x8 a1 = *(const bf16x8*)(Ap + k0 + 8);
    bf16x8 b0 = *(const bf16x8*)(Bp + k0);
    bf16x8 b1 = *(const bf16x8*)(Bp + k0 + 8);
    __syncthreads();
    *(bf16x8*)(As + srow * 40 + soff) = a0;
    *(bf16x8*)(As + srow * 40 + soff + 8) = a1;
    *(bf16x8*)(Bs + srow * 40 + soff) = b0;
    *(bf16x8*)(Bs + srow * 40 + soff + 8) = b1;
    __syncthreads();
    bf16x8 af[4], bfr[4];
#pragma unroll
    for (int m = 0; m < 4; m++) af[m] = *(const bf16x8*)(As + (wm + m * 16 + l15) * 40 + 8 * lh);
#pragma unroll
    for (int n = 0; n < 4; n++) bfr[n] = *(const bf16x8*)(Bs + (wn + n * 16 + l15) * 40 + 8 * lh);
#pragma unroll
    for (int m = 0; m < 4; m++)
#pragma unroll
      for (int n = 0; n < 4; n++)
        acc[m][n] = MFMA16(af[m], bfr[n], acc[m][n]);
  }

#pragma unroll
  for (int nn = 0; nn < 4; nn++) {
    int e = n0 + wn + nn * 16 + l15;
    float bv = bo[e];
#pragma unroll
    for (int mm = 0; mm < 4; mm++) {
#pragma unroll
      for (int r = 0; r < 4; r++) {
        int i = m0 + wm + mm * 16 + lh * 4 + r;
        out[(size_t)i * 1024 + e] = acc[mm][nn][r] + bv;
      }
    }
  }
}

extern "C" void kernel_launch(void* const* d_in, const int* in_sizes, int n_in,
                              void* d_out, int out_size, void* d_ws, size_t ws_size,
                              hipStream_t stream) {
  (void)in_sizes; (void)n_in; (void)out_size; (void)ws_size;
  const float* x     = (const float*)d_in[0];
  const float* w_qkv = (const float*)d_in[1];
  const float* b_qkv = (const float*)d_in[2];
  const float* w_o   = (const float*)d_in[3];
  const float* b_o   = (const float*)d_in[4];
  float* out = (float*)d_out;
  char* ws = (char*)d_ws;

  short* xb     = (short*)(ws);               // 16.8 MB  [8192][1024]
  short* wqkvbT = (short*)(ws + 16777216);    //  6.3 MB  [3072][1024]
  short* wobT   = (short*)(ws + 23068672);    //  2.1 MB  [1024][1024]
  short* Qb     = (short*)(ws + 25165824);    // 16.8 MB  [64][2048][64]
  short* Kb     = (short*)(ws + 41943040);    // 16.8 MB  [64][2048][64]
  short* Vt     = (short*)(ws + 58720256);    // 16.8 MB  [64][64][2048]
  short* Wt     = (short*)(ws + 75497472);    // 16.8 MB  [8192][1024]

  hipLaunchKernelGGL(cvt_x,    dim3(8192),    dim3(256), 0, stream, (const float4*)x, (s16x4*)xb);
  hipLaunchKernelGGL(cvt_wqkv, dim3(96, 32),  dim3(256), 0, stream, w_qkv, wqkvbT);
  hipLaunchKernelGGL(cvt_wo,   dim3(4096),    dim3(256), 0, stream, w_o, wobT);
  hipLaunchKernelGGL(gemm_qkv, dim3(64, 24),  dim3(256), 0, stream, xb, wqkvbT, b_qkv, Qb, Kb, Vt);
  hipLaunchKernelGGL(attn,     dim3(2048),    dim3(256), 0, stream, Qb, Kb, Vt, Wt);
  hipLaunchKernelGGL(gemm_o,   dim3(64, 8),   dim3(256), 0, stream, Wt, wobT, b_o, out);
}

// Round 3
// 238.346 us; speedup vs baseline: 2.4436x; 2.4338x over previous
//
#include <hip/hip_runtime.h>

typedef __attribute__((ext_vector_type(8))) short bf16x8;
typedef __attribute__((ext_vector_type(4))) short s16x4;
typedef __attribute__((ext_vector_type(4))) float f32x4;

#define MFMA16(a,b,c) __builtin_amdgcn_mfma_f32_16x16x32_bf16((a),(b),(c),0,0,0)

static constexpr int Bsz = 4, T = 2048, E = 1024, NH = 16, HP = 64;
static constexpr int BT = Bsz * T;      // 8192
static constexpr int J3 = NH * 3 * HP;  // 3072

__device__ __forceinline__ short f2bf(float f) {
  union { float f; unsigned u; } v; v.f = f;
  unsigned r = (v.u + 0x7fffu + ((v.u >> 16) & 1u)) >> 16;
  return (short)r;
}

// ---------------- converts ----------------
__global__ void cvt_x(const float4* __restrict__ x, s16x4* __restrict__ xb) {
  int i = blockIdx.x * 256 + threadIdx.x;
  float4 v = x[i];
  s16x4 r;
  r[0] = f2bf(v.x); r[1] = f2bf(v.y); r[2] = f2bf(v.z); r[3] = f2bf(v.w);
  xb[i] = r;
}

// w_qkv [E=1024][J=3072] f32  ->  wt [J][E] bf16 (B^T layout)
__global__ void cvt_wqkv(const float* __restrict__ w, short* __restrict__ wt) {
  __shared__ float tile[32][33];
  int jb = blockIdx.x * 32, eb = blockIdx.y * 32;
  int tx = threadIdx.x & 31, ty = threadIdx.x >> 5;   // 32x8
  for (int r = 0; r < 32; r += 8)
    tile[ty + r][tx] = w[(size_t)(eb + ty + r) * J3 + jb + tx];
  __syncthreads();
  for (int r = 0; r < 32; r += 8)
    wt[(size_t)(jb + ty + r) * E + eb + tx] = f2bf(tile[tx][ty + r]);
}

// w_o [P=64][N=16][E=1024] f32 -> wt [e][k'=n*64+p] bf16 (B^T layout)
__global__ void cvt_wo(const float* __restrict__ w, short* __restrict__ wt) {
  int o = blockIdx.x * 256 + threadIdx.x;
  int e = o >> 10, k = o & 1023;
  int n = k >> 6, p = k & 63;
  wt[o] = f2bf(w[(size_t)(p * 16 + n) * E + e]);
}

// ---------------- GEMM1: qkv = x @ w_qkv, scatter to Q (scaled), K, V^T ----------------
__global__ __launch_bounds__(256) void gemm_qkv(
    const short* __restrict__ A,    // xb [8192][1024]
    const short* __restrict__ Bt,   // wqkvbT [3072][1024]
    const float* __restrict__ bias, // b_qkv flat [3072]
    short* __restrict__ Qb, short* __restrict__ Kb, short* __restrict__ Vt) {
  __shared__ short As[128 * 40];
  __shared__ short Bs[128 * 40];
  const int m0 = blockIdx.x * 128, n0 = blockIdx.y * 128;
  const int tid = threadIdx.x;
  const int lane = tid & 63, w = tid >> 6;
  const int wm = (w >> 1) * 64, wn = (w & 1) * 64;
  const int l15 = lane & 15, lh = lane >> 4;
  const int srow = tid >> 1, soff = (tid & 1) * 16;

  const short* Ap = A + (size_t)(m0 + srow) * 1024 + soff;
  const short* Bp = Bt + (size_t)(n0 + srow) * 1024 + soff;
  f32x4 acc[4][4] = {};

  for (int k0 = 0; k0 < 1024; k0 += 32) {
    bf16x8 a0 = *(const bf16x8*)(Ap + k0);
    bf16x8 a1 = *(const bf16x8*)(Ap + k0 + 8);
    bf16x8 b0 = *(const bf16x8*)(Bp + k0);
    bf16x8 b1 = *(const bf16x8*)(Bp + k0 + 8);
    __syncthreads();
    *(bf16x8*)(As + srow * 40 + soff) = a0;
    *(bf16x8*)(As + srow * 40 + soff + 8) = a1;
    *(bf16x8*)(Bs + srow * 40 + soff) = b0;
    *(bf16x8*)(Bs + srow * 40 + soff + 8) = b1;
    __syncthreads();
    bf16x8 af[4], bfr[4];
#pragma unroll
    for (int m = 0; m < 4; m++) af[m] = *(const bf16x8*)(As + (wm + m * 16 + l15) * 40 + 8 * lh);
#pragma unroll
    for (int n = 0; n < 4; n++) bfr[n] = *(const bf16x8*)(Bs + (wn + n * 16 + l15) * 40 + 8 * lh);
#pragma unroll
    for (int m = 0; m < 4; m++)
#pragma unroll
      for (int n = 0; n < 4; n++)
        acc[m][n] = MFMA16(af[m], bfr[n], acc[m][n]);
  }

#pragma unroll
  for (int nn = 0; nn < 4; nn++) {
    int j = n0 + wn + nn * 16 + l15;
    int nh = j / 192, c = j - nh * 192;
    int ty = c >> 6, p = c & 63;
    float bv = bias[j];
#pragma unroll
    for (int mm = 0; mm < 4; mm++) {
#pragma unroll
      for (int r = 0; r < 4; r++) {
        int i = m0 + wm + mm * 16 + lh * 4 + r;
        int bb = i >> 11, tt = i & 2047;
        float val = acc[mm][nn][r] + bv;
        size_t qk = (((size_t)(bb * 16 + nh) * 2048 + tt) << 6) + p;
        // fold 1/sqrt(P) * log2(e) into Q so attention can use raw exp2
        if (ty == 0)      Qb[qk] = f2bf(val * 0.180336880f);
        else if (ty == 1) Kb[qk] = f2bf(val);
        else Vt[(((size_t)(bb * 16 + nh) << 6) + p) * 2048 + tt] = f2bf(val);  // V transposed
      }
    }
  }
}

// ---------------- flash attention: 8 waves/block, 256 q-rows, staged K/V ----------------
// bn = bid & 63 pins each head to one XCD (bid%8 == bn%8).
// K/V tiles (64x64) staged in LDS (pad-72 rows), double-buffered, reg prefetch.
// Swapped-operand form: S^T = mfma(K,Q), O^T = mfma(Vt,P); lane-local softmax state.
__global__ __launch_bounds__(512, 4) void attn(
    const short* __restrict__ Qb, const short* __restrict__ Kb,
    const short* __restrict__ Vt, short* __restrict__ Wt) {
  __shared__ short Kl[2][64 * 72];
  __shared__ short Vl[2][64 * 72];
  __shared__ short Pl[8][16 * 72];
  const int bid = blockIdx.x;            // 512
  const int bn = bid & 63, qc = bid >> 6;
  const int tid = threadIdx.x, lane = tid & 63, w = tid >> 6;
  const int l15 = lane & 15, lh = lane >> 4;
  const int q0 = qc * 256 + w * 32;

  const short* Qp = Qb + ((size_t)bn * 2048 + q0) * 64;
  const short* Kg = Kb + (size_t)bn * 2048 * 64 + (tid >> 3) * 64 + (tid & 7) * 8;
  const short* Vg = Vt + (size_t)bn * 64 * 2048 + (tid >> 3) * 2048 + (tid & 7) * 8;
  short* Pw = &Pl[w][0];
  const int sdst = (tid >> 3) * 72 + (tid & 7) * 8;

  // Q fragments (B-operand): rows q = q0 + qg*16 + l15
  bf16x8 qf[2][2];
#pragma unroll
  for (int qg = 0; qg < 2; qg++)
#pragma unroll
    for (int c = 0; c < 2; c++)
      qf[qg][c] = *(const bf16x8*)(Qp + (qg * 16 + l15) * 64 + c * 32 + 8 * lh);

  float m[2] = {-1e30f, -1e30f}, l[2] = {0.f, 0.f};
  f32x4 o[4][2] = {};
  const f32x4 zero = {0.f, 0.f, 0.f, 0.f};

  // prologue: stage tile 0
  {
    bf16x8 k0 = *(const bf16x8*)Kg;
    bf16x8 v0 = *(const bf16x8*)Vg;
    *(bf16x8*)(&Kl[0][sdst]) = k0;
    *(bf16x8*)(&Vl[0][sdst]) = v0;
  }
  __syncthreads();

  for (int t = 0; t < 32; t++) {
    const int cur = t & 1;
    bf16x8 kreg, vreg;
    if (t < 31) {                               // prefetch next tile -> regs
      kreg = *(const bf16x8*)(Kg + (t + 1) * 4096);
      vreg = *(const bf16x8*)(Vg + (t + 1) * 64);
    }
    const short* Kc = &Kl[cur][0];
    const short* Vc = &Vl[cur][0];

    // QK^T (swapped) for both q-groups; K frags read once
    f32x4 s[4][2];
#pragma unroll
    for (int sub = 0; sub < 4; sub++) {
      bf16x8 k0 = *(const bf16x8*)(Kc + (sub * 16 + l15) * 72 + 8 * lh);
      bf16x8 k1 = *(const bf16x8*)(Kc + (sub * 16 + l15) * 72 + 32 + 8 * lh);
#pragma unroll
      for (int qg = 0; qg < 2; qg++) {
        f32x4 tt = MFMA16(k0, qf[qg][0], zero);
        s[sub][qg] = MFMA16(k1, qf[qg][1], tt);
      }
    }

#pragma unroll
    for (int qg = 0; qg < 2; qg++) {
      // row max: 16 in-lane + 2 shfl
      float pmax = fmaxf(fmaxf(s[0][qg][0], s[0][qg][1]), fmaxf(s[0][qg][2], s[0][qg][3]));
#pragma unroll
      for (int sub = 1; sub < 4; sub++)
        pmax = fmaxf(pmax, fmaxf(fmaxf(s[sub][qg][0], s[sub][qg][1]),
                                 fmaxf(s[sub][qg][2], s[sub][qg][3])));
      pmax = fmaxf(pmax, __shfl_xor(pmax, 16, 64));
      pmax = fmaxf(pmax, __shfl_xor(pmax, 32, 64));
      // defer-max: only rescale when the running max grows materially
      if (!__all(pmax - m[qg] <= 8.f)) {
        float mn = fmaxf(m[qg], pmax);
        float corr = __builtin_amdgcn_exp2f(m[qg] - mn);
        m[qg] = mn;
        l[qg] *= corr;
#pragma unroll
        for (int psub = 0; psub < 4; psub++)
#pragma unroll
          for (int r = 0; r < 4; r++) o[psub][qg][r] *= corr;
      }
      // P = exp2(s - m), sum, pack to LDS (wave-private, in-order DS pipe)
      float ps = 0.f;
#pragma unroll
      for (int sub = 0; sub < 4; sub++) {
        s16x4 pk;
#pragma unroll
        for (int r = 0; r < 4; r++) {
          float pv = __builtin_amdgcn_exp2f(s[sub][qg][r] - m[qg]);
          ps += pv;
          pk[r] = f2bf(pv);
        }
        *(s16x4*)(Pw + l15 * 72 + sub * 16 + lh * 4) = pk;
      }
      ps += __shfl_xor(ps, 16, 64);
      ps += __shfl_xor(ps, 32, 64);
      l[qg] += ps;
      // PV (swapped): A = Vt rows (p) from LDS, B = P rows (q) from LDS
      bf16x8 pa0 = *(const bf16x8*)(Pw + l15 * 72 + 8 * lh);
      bf16x8 pa1 = *(const bf16x8*)(Pw + l15 * 72 + 32 + 8 * lh);
#pragma unroll
      for (int psub = 0; psub < 4; psub++) {
        bf16x8 v0 = *(const bf16x8*)(Vc + (psub * 16 + l15) * 72 + 8 * lh);
        bf16x8 v1 = *(const bf16x8*)(Vc + (psub * 16 + l15) * 72 + 32 + 8 * lh);
        o[psub][qg] = MFMA16(v0, pa0, o[psub][qg]);
        o[psub][qg] = MFMA16(v1, pa1, o[psub][qg]);
      }
    }

    if (t < 31) {                               // write prefetched tile
      *(bf16x8*)(&Kl[cur ^ 1][sdst]) = kreg;
      *(bf16x8*)(&Vl[cur ^ 1][sdst]) = vreg;
    }
    __syncthreads();
  }

  const int bb = bn >> 4, n = bn & 15;
#pragma unroll
  for (int qg = 0; qg < 2; qg++) {
    const float invl = 1.0f / l[qg];
    short* wrow = Wt + (size_t)(bb * 2048 + q0 + qg * 16 + l15) * 1024 + n * 64;
#pragma unroll
    for (int psub = 0; psub < 4; psub++) {
      s16x4 pk;
#pragma unroll
      for (int r = 0; r < 4; r++) pk[r] = f2bf(o[psub][qg][r] * invl);
      *(s16x4*)(wrow + psub * 16 + lh * 4) = pk;
    }
  }
}

// ---------------- GEMM2: out = weighted @ w_o + b_o (f32 out) ----------------
__global__ __launch_bounds__(256) void gemm_o(
    const short* __restrict__ A,   // Wt [8192][1024]
    const short* __restrict__ Bt,  // wobT [1024][1024]
    const float* __restrict__ bo,  // [1024]
    float* __restrict__ out) {     // [8192][1024]
  __shared__ short As[128 * 40];
  __shared__ short Bs[128 * 40];
  const int m0 = blockIdx.x * 128, n0 = blockIdx.y * 128;
  const int tid = threadIdx.x;
  const int lane = tid & 63, w = tid >> 6;
  const int wm = (w >> 1) * 64, wn = (w & 1) * 64;
  const int l15 = lane & 15, lh = lane >> 4;
  const int srow = tid >> 1, soff = (tid & 1) * 16;

  const short* Ap = A + (size_t)(m0 + srow) * 1024 + soff;
  const short* Bp = Bt + (size_t)(n0 + srow) * 1024 + soff;
  f32x4 acc[4][4] = {};

  for (int k0 = 0; k0 < 1024; k0 += 32) {
    bf16x8 a0 = *(const bf16x8*)(Ap + k0);
    bf16x8 a1 = *(const bf16x8*)(Ap + k0 + 8);
    bf16x8 b0 = *(const bf16x8*)(Bp + k0);
    bf16x8 b1 = *(const bf16x8*)(Bp + k0 + 8);
    __syncthreads();
    *(bf16x8*)(As + srow * 40 + soff) = a0;
    *(bf16x8*)(As + srow * 40 + soff + 8) = a1;
    *(bf16x8*)(Bs + srow * 40 + soff) = b0;
    *(bf16x8*)(Bs + srow * 40 + soff + 8) = b1;
    __syncthreads();
    bf16x8 af[4], bfr[4];
#pragma unroll
    for (int m = 0; m < 4; m++) af[m] = *(const bf16x8*)(As + (wm + m * 16 + l15) * 40 + 8 * lh);
#pragma unroll
    for (int n = 0; n < 4; n++) bfr[n] = *(const bf16x8*)(Bs + (wn + n * 16 + l15) * 40 + 8 * lh);
#pragma unroll
    for (int m = 0; m < 4; m++)
#pragma unroll
      for (int n = 0; n < 4; n++)
        acc[m][n] = MFMA16(af[m], bfr[n], acc[m][n]);
  }

#pragma unroll
  for (int nn = 0; nn < 4; nn++) {
    int e = n0 + wn + nn * 16 + l15;
    float bv = bo[e];
#pragma unroll
    for (int mm = 0; mm < 4; mm++) {
#pragma unroll
      for (int r = 0; r < 4; r++) {
        int i = m0 + wm + mm * 16 + lh * 4 + r;
        out[(size_t)i * 1024 + e] = acc[mm][nn][r] + bv;
      }
    }
  }
}

extern "C" void kernel_launch(void* const* d_in, const int* in_sizes, int n_in,
                              void* d_out, int out_size, void* d_ws, size_t ws_size,
                              hipStream_t stream) {
  (void)in_sizes; (void)n_in; (void)out_size; (void)ws_size;
  const float* x     = (const float*)d_in[0];
  const float* w_qkv = (const float*)d_in[1];
  const float* b_qkv = (const float*)d_in[2];
  const float* w_o   = (const float*)d_in[3];
  const float* b_o   = (const float*)d_in[4];
  float* out = (float*)d_out;
  char* ws = (char*)d_ws;

  short* xb     = (short*)(ws);               // 16.8 MB  [8192][1024]
  short* wqkvbT = (short*)(ws + 16777216);    //  6.3 MB  [3072][1024]
  short* wobT   = (short*)(ws + 23068672);    //  2.1 MB  [1024][1024]
  short* Qb     = (short*)(ws + 25165824);    // 16.8 MB  [64][2048][64]
  short* Kb     = (short*)(ws + 41943040);    // 16.8 MB  [64][2048][64]
  short* Vt     = (short*)(ws + 58720256);    // 16.8 MB  [64][64][2048]
  short* Wt     = (short*)(ws + 75497472);    // 16.8 MB  [8192][1024]

  hipLaunchKernelGGL(cvt_x,    dim3(8192),    dim3(256), 0, stream, (const float4*)x, (s16x4*)xb);
  hipLaunchKernelGGL(cvt_wqkv, dim3(96, 32),  dim3(256), 0, stream, w_qkv, wqkvbT);
  hipLaunchKernelGGL(cvt_wo,   dim3(4096),    dim3(256), 0, stream, w_o, wobT);
  hipLaunchKernelGGL(gemm_qkv, dim3(64, 24),  dim3(256), 0, stream, xb, wqkvbT, b_qkv, Qb, Kb, Vt);
  hipLaunchKernelGGL(attn,     dim3(512),     dim3(512), 0, stream, Qb, Kb, Vt, Wt);
  hipLaunchKernelGGL(gemm_o,   dim3(64, 8),   dim3(256), 0, stream, Wt, wobT, b_o, out);
}

// Round 4
// 205.406 us; speedup vs baseline: 2.8355x; 1.1604x over previous
//
#include <hip/hip_runtime.h>

typedef __attribute__((ext_vector_type(8))) short bf16x8;
typedef __attribute__((ext_vector_type(4))) short s16x4;
typedef __attribute__((ext_vector_type(4))) float f32x4;
typedef __attribute__((ext_vector_type(2))) unsigned u32x2;

#define MFMA16(a,b,c) __builtin_amdgcn_mfma_f32_16x16x32_bf16((a),(b),(c),0,0,0)

static constexpr int Bsz = 4, T = 2048, E = 1024, NH = 16, HP = 64;
static constexpr int J3 = NH * 3 * HP;  // 3072

__device__ __forceinline__ short f2bf(float f) {
  union { float f; unsigned u; } v; v.f = f;
  unsigned r = (v.u + 0x7fffu + ((v.u >> 16) & 1u)) >> 16;
  return (short)r;
}

__device__ __forceinline__ unsigned cvtpk(float a, float b) {
  unsigned r;
  asm("v_cvt_pk_bf16_f32 %0, %1, %2" : "=v"(r) : "v"(a), "v"(b));
  return r;
}

typedef __attribute__((address_space(3))) unsigned int lds_u32;
typedef __attribute__((address_space(1))) const unsigned int glb_u32;
// async global->LDS, 16 B/lane; LDS dest = wave-uniform base + lane*16
__device__ __forceinline__ void gl16(const short* g, const short* l) {
  __builtin_amdgcn_global_load_lds((glb_u32*)g, (lds_u32*)l, 16, 0, 0);
}

// ---------------- converts ----------------
__global__ void cvt_x(const float4* __restrict__ x, s16x4* __restrict__ xb) {
  int i = blockIdx.x * 256 + threadIdx.x;
  float4 v = x[i];
  s16x4 r;
  r[0] = f2bf(v.x); r[1] = f2bf(v.y); r[2] = f2bf(v.z); r[3] = f2bf(v.w);
  xb[i] = r;
}

// w_qkv [E=1024][J=3072] f32  ->  wt [J][E] bf16 (B^T layout)
__global__ void cvt_wqkv(const float* __restrict__ w, short* __restrict__ wt) {
  __shared__ float tile[32][33];
  int jb = blockIdx.x * 32, eb = blockIdx.y * 32;
  int tx = threadIdx.x & 31, ty = threadIdx.x >> 5;   // 32x8
  for (int r = 0; r < 32; r += 8)
    tile[ty + r][tx] = w[(size_t)(eb + ty + r) * J3 + jb + tx];
  __syncthreads();
  for (int r = 0; r < 32; r += 8)
    wt[(size_t)(jb + ty + r) * E + eb + tx] = f2bf(tile[tx][ty + r]);
}

// w_o [P=64][N=16][E=1024] f32 -> wt [e][k'=n*64+p] bf16 (B^T layout)
__global__ void cvt_wo(const float* __restrict__ w, short* __restrict__ wt) {
  int o = blockIdx.x * 256 + threadIdx.x;
  int e = o >> 10, k = o & 1023;
  int n = k >> 6, p = k & 63;
  wt[o] = f2bf(w[(size_t)(p * 16 + n) * E + e]);
}

// ---------------- GEMM1: qkv = x @ w_qkv, scatter to Q (scaled), K, V^T ----------------
// 128x128 tile, BK=64, global_load_lds staging, XOR-swizzled LDS (16B blocks).
__global__ __launch_bounds__(256) void gemm_qkv(
    const short* __restrict__ A,    // xb [8192][1024]
    const short* __restrict__ Bt,   // wqkvbT [3072][1024]
    const float* __restrict__ bias, // b_qkv flat [3072]
    short* __restrict__ Qb, short* __restrict__ Kb, short* __restrict__ Vt) {
  __shared__ short As[128 * 64];
  __shared__ short Bs[128 * 64];
  const int m0 = blockIdx.x * 128, n0 = blockIdx.y * 128;
  const int tid = threadIdx.x;
  const int lane = tid & 63, w = tid >> 6;
  const int wm = (w >> 1) * 64, wn = (w & 1) * 64;
  const int l15 = lane & 15, lh = lane >> 4;
  const int l7 = l15 & 7;

  // staging: wave w stages rows w*32..w*32+31 (4 chunks of 8 rows)
  const int rA = lane >> 3;                       // row within chunk
  const int cS = 8 * ((lane & 7) ^ rA);           // pre-swizzled source col (shorts)
  const short* Ap = A + (size_t)(m0 + w * 32 + rA) * 1024 + cS;
  const short* Bp = Bt + (size_t)(n0 + w * 32 + rA) * 1024 + cS;
  const short* AsBase = As + w * 2048;            // chunk base (shorts): (w*4+j)*512
  const short* BsBase = Bs + w * 2048;

  f32x4 acc[4][4] = {};

  for (int k0 = 0; k0 < 1024; k0 += 64) {
    __syncthreads();                              // prev compute done
#pragma unroll
    for (int j = 0; j < 4; j++) {
      gl16(Ap + j * 8192 + k0, AsBase + j * 512);
      gl16(Bp + j * 8192 + k0, BsBase + j * 512);
    }
    __syncthreads();                              // vmcnt(0) drain before reads
    bf16x8 af[2][4], bfr[2][4];
#pragma unroll
    for (int kk = 0; kk < 2; kk++) {
#pragma unroll
      for (int m = 0; m < 4; m++)
        af[kk][m] = *(const bf16x8*)(As + (wm + m * 16 + l15) * 64 + 8 * ((kk * 4 + lh) ^ l7));
#pragma unroll
      for (int n = 0; n < 4; n++)
        bfr[kk][n] = *(const bf16x8*)(Bs + (wn + n * 16 + l15) * 64 + 8 * ((kk * 4 + lh) ^ l7));
    }
#pragma unroll
    for (int m = 0; m < 4; m++)
#pragma unroll
      for (int n = 0; n < 4; n++) {
        acc[m][n] = MFMA16(af[0][m], bfr[0][n], acc[m][n]);
        acc[m][n] = MFMA16(af[1][m], bfr[1][n], acc[m][n]);
      }
  }

#pragma unroll
  for (int nn = 0; nn < 4; nn++) {
    int j = n0 + wn + nn * 16 + l15;
    int nh = j / 192, c = j - nh * 192;
    int ty = c >> 6, p = c & 63;
    float bv = bias[j];
#pragma unroll
    for (int mm = 0; mm < 4; mm++) {
#pragma unroll
      for (int r = 0; r < 4; r++) {
        int i = m0 + wm + mm * 16 + lh * 4 + r;
        int bb = i >> 11, tt = i & 2047;
        float val = acc[mm][nn][r] + bv;
        size_t qk = (((size_t)(bb * 16 + nh) * 2048 + tt) << 6) + p;
        // fold 1/sqrt(P) * log2(e) into Q so attention can use raw exp2
        if (ty == 0)      Qb[qk] = f2bf(val * 0.180336880f);
        else if (ty == 1) Kb[qk] = f2bf(val);
        else Vt[(((size_t)(bb * 16 + nh) << 6) + p) * 2048 + tt] = f2bf(val);  // V transposed
      }
    }
  }
}

// ---------------- flash attention: 8 waves, 256 q-rows, gl_lds-staged swizzled K/V ----------------
__global__ __launch_bounds__(512, 4) void attn(
    const short* __restrict__ Qb, const short* __restrict__ Kb,
    const short* __restrict__ Vt, short* __restrict__ Wt) {
  __shared__ short Kl[2][64 * 64];        // 8 KB each buf, XOR-swizzled rows (128 B)
  __shared__ short Vl[2][64 * 64];
  __shared__ short Pl[8][2][16 * 64];     // per wave, per q-group; swizzled
  const int bid = blockIdx.x;             // 512
  const int bn = bid & 63, qc = bid >> 6; // head -> fixed XCD
  const int tid = threadIdx.x, lane = tid & 63, w = tid >> 6;
  const int l15 = lane & 15, lh = lane >> 4;
  const int l7 = l15 & 7;
  const int q0 = qc * 256 + w * 32;

  const short* Qp = Qb + ((size_t)bn * 2048 + q0) * 64;
  // staging: wave w stages rows w*8..w*8+7 of each 64-row tile
  const int rA = lane >> 3;
  const int cS = 8 * ((lane & 7) ^ rA);
  const short* Kg = Kb + (size_t)bn * 2048 * 64 + (w * 8 + rA) * 64 + cS;
  const short* Vg = Vt + (size_t)bn * 64 * 2048 + (size_t)(w * 8 + rA) * 2048 + cS;

  // Q fragments (B-operand): rows q = q0 + qg*16 + l15
  bf16x8 qf[2][2];
#pragma unroll
  for (int qg = 0; qg < 2; qg++)
#pragma unroll
    for (int c = 0; c < 2; c++)
      qf[qg][c] = *(const bf16x8*)(Qp + (qg * 16 + l15) * 64 + c * 32 + 8 * lh);

  float m[2] = {-1e30f, -1e30f}, l[2] = {0.f, 0.f};
  f32x4 o[4][2] = {};
  const f32x4 zero = {0.f, 0.f, 0.f, 0.f};

  // prologue: stage tile 0 into buf 0
  gl16(Kg, &Kl[0][w * 512]);
  gl16(Vg, &Vl[0][w * 512]);
  __syncthreads();

  for (int t = 0; t < 32; t++) {
    const int cur = t & 1;
    if (t < 31) {                          // async prefetch next tile -> other buf
      gl16(Kg + (t + 1) * 4096, &Kl[cur ^ 1][w * 512]);
      gl16(Vg + (t + 1) * 64,   &Vl[cur ^ 1][w * 512]);
    }
    const short* Kc = &Kl[cur][0];
    const short* Vc = &Vl[cur][0];

    // QK^T (swapped): s[sub][qg][r] = S[kv=sub*16+lh*4+r][q=q0+qg*16+l15]
    f32x4 s[4][2];
#pragma unroll
    for (int sub = 0; sub < 4; sub++) {
      const short* kr = Kc + (sub * 16 + l15) * 64;
      bf16x8 k0 = *(const bf16x8*)(kr + 8 * (lh ^ l7));
      bf16x8 k1 = *(const bf16x8*)(kr + 8 * ((4 + lh) ^ l7));
#pragma unroll
      for (int qg = 0; qg < 2; qg++) {
        f32x4 tt = MFMA16(k0, qf[qg][0], zero);
        s[sub][qg] = MFMA16(k1, qf[qg][1], tt);
      }
    }

    // softmax both q-groups, P -> LDS (swizzled, cvt_pk packed)
#pragma unroll
    for (int qg = 0; qg < 2; qg++) {
      float pmax = fmaxf(fmaxf(s[0][qg][0], s[0][qg][1]), fmaxf(s[0][qg][2], s[0][qg][3]));
#pragma unroll
      for (int sub = 1; sub < 4; sub++)
        pmax = fmaxf(pmax, fmaxf(fmaxf(s[sub][qg][0], s[sub][qg][1]),
                                 fmaxf(s[sub][qg][2], s[sub][qg][3])));
      pmax = fmaxf(pmax, __shfl_xor(pmax, 16, 64));
      pmax = fmaxf(pmax, __shfl_xor(pmax, 32, 64));
      if (!__all(pmax - m[qg] <= 8.f)) {   // defer-max (T13)
        float mn = fmaxf(m[qg], pmax);
        float corr = __builtin_amdgcn_exp2f(m[qg] - mn);
        m[qg] = mn;
        l[qg] *= corr;
#pragma unroll
        for (int psub = 0; psub < 4; psub++)
#pragma unroll
          for (int r = 0; r < 4; r++) o[psub][qg][r] *= corr;
      }
      char* Pw = (char*)&Pl[w][qg][0] + l15 * 128;
      float ps = 0.f;
#pragma unroll
      for (int sub = 0; sub < 4; sub++) {
        float pv0 = __builtin_amdgcn_exp2f(s[sub][qg][0] - m[qg]);
        float pv1 = __builtin_amdgcn_exp2f(s[sub][qg][1] - m[qg]);
        float pv2 = __builtin_amdgcn_exp2f(s[sub][qg][2] - m[qg]);
        float pv3 = __builtin_amdgcn_exp2f(s[sub][qg][3] - m[qg]);
        ps += (pv0 + pv1) + (pv2 + pv3);
        u32x2 pk = {cvtpk(pv0, pv1), cvtpk(pv2, pv3)};
        *(u32x2*)(Pw + ((sub * 32 + lh * 8) ^ (l7 << 4))) = pk;
      }
      ps += __shfl_xor(ps, 16, 64);
      ps += __shfl_xor(ps, 32, 64);
      l[qg] += ps;
    }

    // PV (swapped): A = V rows (p), B = P rows (q); V frags read ONCE for both qg
    bf16x8 pa[2][2];
#pragma unroll
    for (int qg = 0; qg < 2; qg++) {
      const short* pr = &Pl[w][qg][0] + l15 * 64;
      pa[qg][0] = *(const bf16x8*)(pr + 8 * (lh ^ l7));
      pa[qg][1] = *(const bf16x8*)(pr + 8 * ((4 + lh) ^ l7));
    }
#pragma unroll
    for (int psub = 0; psub < 4; psub++) {
      const short* vr = Vc + (psub * 16 + l15) * 64;
      bf16x8 v0 = *(const bf16x8*)(vr + 8 * (lh ^ l7));
      bf16x8 v1 = *(const bf16x8*)(vr + 8 * ((4 + lh) ^ l7));
#pragma unroll
      for (int qg = 0; qg < 2; qg++) {
        o[psub][qg] = MFMA16(v0, pa[qg][0], o[psub][qg]);
        o[psub][qg] = MFMA16(v1, pa[qg][1], o[psub][qg]);
      }
    }
    __syncthreads();   // drains prefetch (vmcnt) + all LDS reads before buffer swap
  }

  const int bb = bn >> 4, n = bn & 15;
#pragma unroll
  for (int qg = 0; qg < 2; qg++) {
    const float invl = 1.0f / l[qg];
    short* wrow = Wt + (size_t)(bb * 2048 + q0 + qg * 16 + l15) * 1024 + n * 64;
#pragma unroll
    for (int psub = 0; psub < 4; psub++) {
      s16x4 pk;
#pragma unroll
      for (int r = 0; r < 4; r++) pk[r] = f2bf(o[psub][qg][r] * invl);
      *(s16x4*)(wrow + psub * 16 + lh * 4) = pk;
    }
  }
}

// ---------------- GEMM2: out = weighted @ w_o + b_o (f32 out) ----------------
__global__ __launch_bounds__(256) void gemm_o(
    const short* __restrict__ A,   // Wt [8192][1024]
    const short* __restrict__ Bt,  // wobT [1024][1024]
    const float* __restrict__ bo,  // [1024]
    float* __restrict__ out) {     // [8192][1024]
  __shared__ short As[128 * 64];
  __shared__ short Bs[128 * 64];
  const int m0 = blockIdx.x * 128, n0 = blockIdx.y * 128;
  const int tid = threadIdx.x;
  const int lane = tid & 63, w = tid >> 6;
  const int wm = (w >> 1) * 64, wn = (w & 1) * 64;
  const int l15 = lane & 15, lh = lane >> 4;
  const int l7 = l15 & 7;

  const int rA = lane >> 3;
  const int cS = 8 * ((lane & 7) ^ rA);
  const short* Ap = A + (size_t)(m0 + w * 32 + rA) * 1024 + cS;
  const short* Bp = Bt + (size_t)(n0 + w * 32 + rA) * 1024 + cS;
  const short* AsBase = As + w * 2048;
  const short* BsBase = Bs + w * 2048;

  f32x4 acc[4][4] = {};

  for (int k0 = 0; k0 < 1024; k0 += 64) {
    __syncthreads();
#pragma unroll
    for (int j = 0; j < 4; j++) {
      gl16(Ap + j * 8192 + k0, AsBase + j * 512);
      gl16(Bp + j * 8192 + k0, BsBase + j * 512);
    }
    __syncthreads();
    bf16x8 af[2][4], bfr[2][4];
#pragma unroll
    for (int kk = 0; kk < 2; kk++) {
#pragma unroll
      for (int m = 0; m < 4; m++)
        af[kk][m] = *(const bf16x8*)(As + (wm + m * 16 + l15) * 64 + 8 * ((kk * 4 + lh) ^ l7));
#pragma unroll
      for (int n = 0; n < 4; n++)
        bfr[kk][n] = *(const bf16x8*)(Bs + (wn + n * 16 + l15) * 64 + 8 * ((kk * 4 + lh) ^ l7));
    }
#pragma unroll
    for (int m = 0; m < 4; m++)
#pragma unroll
      for (int n = 0; n < 4; n++) {
        acc[m][n] = MFMA16(af[0][m], bfr[0][n], acc[m][n]);
        acc[m][n] = MFMA16(af[1][m], bfr[1][n], acc[m][n]);
      }
  }

#pragma unroll
  for (int nn = 0; nn < 4; nn++) {
    int e = n0 + wn + nn * 16 + l15;
    float bv = bo[e];
#pragma unroll
    for (int mm = 0; mm < 4; mm++) {
#pragma unroll
      for (int r = 0; r < 4; r++) {
        int i = m0 + wm + mm * 16 + lh * 4 + r;
        out[(size_t)i * 1024 + e] = acc[mm][nn][r] + bv;
      }
    }
  }
}

extern "C" void kernel_launch(void* const* d_in, const int* in_sizes, int n_in,
                              void* d_out, int out_size, void* d_ws, size_t ws_size,
                              hipStream_t stream) {
  (void)in_sizes; (void)n_in; (void)out_size; (void)ws_size;
  const float* x     = (const float*)d_in[0];
  const float* w_qkv = (const float*)d_in[1];
  const float* b_qkv = (const float*)d_in[2];
  const float* w_o   = (const float*)d_in[3];
  const float* b_o   = (const float*)d_in[4];
  float* out = (float*)d_out;
  char* ws = (char*)d_ws;

  short* xb     = (short*)(ws);               // 16.8 MB  [8192][1024]
  short* wqkvbT = (short*)(ws + 16777216);    //  6.3 MB  [3072][1024]
  short* wobT   = (short*)(ws + 23068672);    //  2.1 MB  [1024][1024]
  short* Qb     = (short*)(ws + 25165824);    // 16.8 MB  [64][2048][64]
  short* Kb     = (short*)(ws + 41943040);    // 16.8 MB  [64][2048][64]
  short* Vt     = (short*)(ws + 58720256);    // 16.8 MB  [64][64][2048]
  short* Wt     = (short*)(ws + 75497472);    // 16.8 MB  [8192][1024]

  hipLaunchKernelGGL(cvt_x,    dim3(8192),    dim3(256), 0, stream, (const float4*)x, (s16x4*)xb);
  hipLaunchKernelGGL(cvt_wqkv, dim3(96, 32),  dim3(256), 0, stream, w_qkv, wqkvbT);
  hipLaunchKernelGGL(cvt_wo,   dim3(4096),    dim3(256), 0, stream, w_o, wobT);
  hipLaunchKernelGGL(gemm_qkv, dim3(64, 24),  dim3(256), 0, stream, xb, wqkvbT, b_qkv, Qb, Kb, Vt);
  hipLaunchKernelGGL(attn,     dim3(512),     dim3(512), 0, stream, Qb, Kb, Vt, Wt);
  hipLaunchKernelGGL(gemm_o,   dim3(64, 8),   dim3(256), 0, stream, Wt, wobT, b_o, out);
}